// Round 6
// baseline (99.727 us; speedup 1.0000x reference)
//
#include <hip/hip_runtime.h>

// ROI head matcher. R5 (resubmit — R5 bench was an infra failure, kernel
// never ran): zero memory instructions in the inner loop.
// 128 GTs split over 16 waves (block=1024); each wave hoists its 8 GT boxes
// + areas into wave-uniform registers ONCE, then runs 8 pure-VALU iterations
// (no LDS, no s_waitcnt). Partials (inter, uni, argidx) combine through LDS
// in two rounds with ADJACENT pairing (2w,2w+1) into a second buffer so every
// merge scans ascending g-ranges -> strict '>' keeps jnp.argmax first-index
// tie semantics exactly.
//
// Argmax compare: exact Dekker cross-product (absmax 0 in R2-R4):
//   inter1/uni1 > inter2/uni2  <=>  (p1+e1) > (p2+e2),  e = fmaf(a,b,-p)
// One IEEE divide in the epilogue reproduces best_match_iou bit-exactly for
// the threshold tests.

#define IOU_THRESHOLD 0.5f
#define LOW_BG_IOU 0.1f

__global__ __launch_bounds__(1024) void roi_match_kernel(
    const float* __restrict__ proposals,   // [N,4]
    const float* __restrict__ gt_boxes,    // [128,4]
    const int*   __restrict__ gt_labels,   // [128]
    float* __restrict__ out,               // [N] labels then [N,4] boxes
    int N)
{
#pragma clang fp contract(off)
    __shared__ float4 s_a[16][64];   // stage-0 partials (16 waves)
    __shared__ float4 s_b[8][64];    // stage-1 partials (8 pairs)

    const int tid  = threadIdx.x;
    const int wave = __builtin_amdgcn_readfirstlane(tid >> 6);
    const int lane = tid & 63;

    const int n  = blockIdx.x * 64 + lane;   // lane <-> proposal, all waves
    const int nc = n < N ? n : N - 1;        // clamp loads; writes guarded

    const float4 p = ((const float4*)proposals)[nc];
    const float area_p = (p.z - p.x) * (p.w - p.y);

    const int g0 = wave * 8;

    // One-time hoist: 8 wave-uniform GT boxes + areas (reference rounding).
    float4 gb[8];
    float  ga[8];
#pragma unroll
    for (int j = 0; j < 8; ++j)
        gb[j] = ((const float4*)gt_boxes)[g0 + j];
#pragma unroll
    for (int j = 0; j < 8; ++j)
        ga[j] = (gb[j].z - gb[j].x) * (gb[j].w - gb[j].y);

    // Sentinel = iou 0 at first index of this wave's range.
    int   bi = g0;
    float inter_b = 0.0f, uni_b = 1.0f;

#pragma unroll
    for (int j = 0; j < 8; ++j) {            // pure VALU, zero memory ops
        float x1 = fmaxf(gb[j].x, p.x);
        float y1 = fmaxf(gb[j].y, p.y);
        float x2 = fminf(gb[j].z, p.z);
        float y2 = fminf(gb[j].w, p.w);
        float iw = fmaxf(x2 - x1, 0.0f);
        float ih = fmaxf(y2 - y1, 0.0f);
        float inter = iw * ih;
        float uni   = (ga[j] + area_p) - inter;

        float p1 = inter * uni_b;            // exact inter*uni_b vs inter_b*uni
        float e1 = fmaf(inter, uni_b, -p1);
        float p2 = inter_b * uni;
        float e2 = fmaf(inter_b, uni, -p2);
        bool gt = (p1 - p2) > (e2 - e1);

        bi      = gt ? g0 + j : bi;
        inter_b = gt ? inter  : inter_b;
        uni_b   = gt ? uni    : uni_b;
    }

    s_a[wave][lane] = make_float4(inter_b, uni_b, __int_as_float(bi), 0.0f);
    __syncthreads();

    if (wave < 8) {                          // round 1: adjacent ranges (2w,2w+1)
        float4 a = s_a[2 * wave][lane];      // lower g-range
        float4 b = s_a[2 * wave + 1][lane];  // higher g-range
        float p1 = b.x * a.y;
        float e1 = fmaf(b.x, a.y, -p1);
        float p2 = a.x * b.y;
        float e2 = fmaf(a.x, b.y, -p2);
        bool gt = (p1 - p2) > (e2 - e1);     // b strictly greater -> replace
        s_b[wave][lane] = gt ? b : a;
    }
    __syncthreads();

    if (wave == 0 && n < N) {                // round 2: scan 8 in ascending order
        float4 best = s_b[0][lane];
#pragma unroll
        for (int w = 1; w < 8; ++w) {
            float4 c = s_b[w][lane];
            float p1 = c.x * best.y;
            float e1 = fmaf(c.x, best.y, -p1);
            float p2 = best.x * c.y;
            float e2 = fmaf(best.x, c.y, -p2);
            bool gt = (p1 - p2) > (e2 - e1);
            best = gt ? c : best;
        }
        int bbi = __float_as_int(best.z);
        float q = best.x / best.y;           // IEEE div == reference max iou

        float lab;
        if (q < LOW_BG_IOU)          lab = -1.0f;               // ignored
        else if (q < IOU_THRESHOLD)  lab = 0.0f;                // background
        else                         lab = (float)gt_labels[bbi];

        out[n] = lab;
        ((float4*)(out + N))[n] = ((const float4*)gt_boxes)[bbi];  // aligned
    }
}

extern "C" void kernel_launch(void* const* d_in, const int* in_sizes, int n_in,
                              void* d_out, int out_size, void* d_ws, size_t ws_size,
                              hipStream_t stream) {
    const float* proposals = (const float*)d_in[0];
    const float* gt_boxes  = (const float*)d_in[1];
    const int*   gt_labels = (const int*)d_in[2];
    float* out = (float*)d_out;

    int N = in_sizes[0] / 4;                 // 200000
    int blocks = (N + 63) / 64;              // 3125 (exact)

    roi_match_kernel<<<blocks, 1024, 0, stream>>>(proposals, gt_boxes,
                                                  gt_labels, out, N);
}

// Round 7
// 78.093 us; speedup vs baseline: 1.2770x; 1.2770x over previous
//
#include <hip/hip_runtime.h>

// ROI head matcher. R7: balance VALU issue / LDS pipe / TLP.
//   block = 128 threads = 2 waves; each block owns 128 proposals.
//   Each lane carries P=2 independent proposals (ILP breaks the loop-carried
//   argmax chain); wave w scans GT half [64w, 64w+64) -> 3126 waves total
//   (~12/CU, same TLP as the best round R4) with HALF the LDS ops and HALF
//   the loop iterations per proposal of R4.
//   Per g-iter: one ds_read_b128 (wave-uniform -> broadcast, conflict-free),
//   area recomputed in VALU with the reference's exact single-rounded ops.
//   Combine: one exact Dekker merge per proposal (upper half replaces only
//   if STRICTLY greater -> jnp.argmax first-index semantics preserved).
//
// Argmax compare: exact Dekker cross-product (absmax 0 in R2-R6):
//   i1/u1 > i2/u2  <=>  (p1+e1) > (p2+e2),  e = fmaf(a,b,-p)
// One IEEE divide in the epilogue reproduces best_match_iou bit-exactly.

#define IOU_THRESHOLD 0.5f
#define LOW_BG_IOU 0.1f
#define BLOCK 128
#define PROPS 128   // proposals per block

__global__ __launch_bounds__(BLOCK) void roi_match_kernel(
    const float* __restrict__ proposals,   // [N,4]
    const float* __restrict__ gt_boxes,    // [128,4]
    const int*   __restrict__ gt_labels,   // [128]
    float* __restrict__ out,               // [N] labels then [N,4] boxes
    int N)
{
#pragma clang fp contract(off)
    __shared__ float4 s_gt[128];
    __shared__ float  s_lab[128];
    __shared__ float4 s_part[2][PROPS];    // [gt-half][proposal slot]

    const int tid  = threadIdx.x;
    const int wave = tid >> 6;
    const int lane = tid & 63;
    const int base = blockIdx.x * PROPS;

    // Stage GT boxes + labels: one record per thread (128 threads, 128 GTs).
    s_gt[tid]  = ((const float4*)gt_boxes)[tid];
    s_lab[tid] = (float)gt_labels[tid];
    __syncthreads();

    // Two proposals per lane (both waves process the same 128 proposals).
    const int n0 = base + lane;
    const int n1 = base + 64 + lane;
    const int c0 = n0 < N ? n0 : N - 1;    // clamp loads; writes guarded
    const int c1 = n1 < N ? n1 : N - 1;
    const float4 P0 = ((const float4*)proposals)[c0];
    const float4 P1 = ((const float4*)proposals)[c1];
    const float a0 = (P0.z - P0.x) * (P0.w - P0.y);
    const float a1 = (P1.z - P1.x) * (P1.w - P1.y);

    const int g0 = wave * 64;
    // Sentinels: iou 0 at the first index of this wave's range.
    int   bi0 = g0, bi1 = g0;
    float ib0 = 0.0f, ub0 = 1.0f;
    float ib1 = 0.0f, ub1 = 1.0f;

#pragma unroll 4
    for (int j = 0; j < 64; ++j) {
        const int g = g0 + j;              // wave-uniform -> LDS broadcast
        const float4 gb = s_gt[g];
        const float garea = (gb.z - gb.x) * (gb.w - gb.y);  // ref rounding

        // proposal 0
        {
            float x1 = fmaxf(gb.x, P0.x);
            float y1 = fmaxf(gb.y, P0.y);
            float x2 = fminf(gb.z, P0.z);
            float y2 = fminf(gb.w, P0.w);
            float iw = fmaxf(x2 - x1, 0.0f);
            float ih = fmaxf(y2 - y1, 0.0f);
            float inter = iw * ih;
            float uni   = (garea + a0) - inter;
            float p1 = inter * ub0;
            float e1 = fmaf(inter, ub0, -p1);
            float p2 = ib0 * uni;
            float e2 = fmaf(ib0, uni, -p2);
            bool gt = (p1 - p2) > (e2 - e1);   // exact
            bi0 = gt ? g     : bi0;
            ib0 = gt ? inter : ib0;
            ub0 = gt ? uni   : ub0;
        }
        // proposal 1 (independent chain -> ILP)
        {
            float x1 = fmaxf(gb.x, P1.x);
            float y1 = fmaxf(gb.y, P1.y);
            float x2 = fminf(gb.z, P1.z);
            float y2 = fminf(gb.w, P1.w);
            float iw = fmaxf(x2 - x1, 0.0f);
            float ih = fmaxf(y2 - y1, 0.0f);
            float inter = iw * ih;
            float uni   = (garea + a1) - inter;
            float p1 = inter * ub1;
            float e1 = fmaf(inter, ub1, -p1);
            float p2 = ib1 * uni;
            float e2 = fmaf(ib1, uni, -p2);
            bool gt = (p1 - p2) > (e2 - e1);
            bi1 = gt ? g     : bi1;
            ib1 = gt ? inter : ib1;
            ub1 = gt ? uni   : ub1;
        }
    }

    s_part[wave][lane]      = make_float4(ib0, ub0, __int_as_float(bi0), 0.0f);
    s_part[wave][lane + 64] = make_float4(ib1, ub1, __int_as_float(bi1), 0.0f);
    __syncthreads();

    // Combine: thread tid owns proposal (base + tid); merge lower/upper halves.
    const int n = base + tid;
    if (n < N) {
        float4 a = s_part[0][tid];         // g in [0,64)  (lower -> wins ties)
        float4 b = s_part[1][tid];         // g in [64,128)
        float p1 = b.x * a.y;
        float e1 = fmaf(b.x, a.y, -p1);
        float p2 = a.x * b.y;
        float e2 = fmaf(a.x, b.y, -p2);
        bool gt = (p1 - p2) > (e2 - e1);   // upper strictly greater
        float4 best = gt ? b : a;

        int bbi = __float_as_int(best.z);
        float q = best.x / best.y;         // IEEE div == reference max iou

        float lab;
        if (q < LOW_BG_IOU)          lab = -1.0f;        // ignored
        else if (q < IOU_THRESHOLD)  lab = 0.0f;         // background
        else                         lab = s_lab[bbi];   // gt label

        out[n] = lab;
        ((float4*)(out + N))[n] = s_gt[bbi];   // offset 800000 B, 16B-aligned
    }
}

extern "C" void kernel_launch(void* const* d_in, const int* in_sizes, int n_in,
                              void* d_out, int out_size, void* d_ws, size_t ws_size,
                              hipStream_t stream) {
    const float* proposals = (const float*)d_in[0];
    const float* gt_boxes  = (const float*)d_in[1];
    const int*   gt_labels = (const int*)d_in[2];
    float* out = (float*)d_out;

    int N = in_sizes[0] / 4;               // 200000
    int blocks = (N + PROPS - 1) / PROPS;  // 1563

    roi_match_kernel<<<blocks, BLOCK, 0, stream>>>(proposals, gt_boxes,
                                                   gt_labels, out, N);
}